// Round 9
// baseline (714.589 us; speedup 1.0000x reference)
//
#include <hip/hip_runtime.h>
#include <hip/hip_bf16.h>
#include <cmath>
#include <cstdint>

// AttentionPoolingAggregator — MI355X round 13 (DIAGNOSTIC)
//  * Five structural theories in a row were neutral (~122-127us): occupancy,
//    stores, barriers, load-ahead, wave granularity. Static model says
//    2.5Kcyc/tile, HW says 23K. Per skill rule "ablate before optimizing":
//    this round launches 4 gemm template variants (V1 no-stores, V2
//    no-compute, V3 no-staging, V0 full) as separate dispatches; rocprof
//    rows give per-phase cost. Garbage outputs of V1-V3 are fully
//    overwritten by V0 before edge runs -> correctness preserved.
//  * Total dur_us will regress this round by design (~+300us of ablation
//    dispatches). Reading: the variant that collapses names the phase.

#define H 256

typedef __attribute__((ext_vector_type(8))) short bfrag;  // 8 bf16 (4 VGPRs)
typedef __attribute__((ext_vector_type(4))) float ffrag;  // 4 fp32 acc

__device__ __forceinline__ ushort f2bf(float f) {  // fp32 -> bf16 RNE
  uint u = __float_as_uint(f);
  uint r = u + 0x7FFFu + ((u >> 16) & 1u);
  return (ushort)(r >> 16);
}
__device__ __forceinline__ float bf2f(ushort h) {
  return __uint_as_float((uint)h << 16);
}

// ---------------- prep: wsplit(W_news) | wsplit(W_company) | count histogram ----------------
__global__ void prep_kernel(const float* __restrict__ Wn, const float* __restrict__ Wc,
                            ushort* __restrict__ WnHi, ushort* __restrict__ WnLo,
                            ushort* __restrict__ WcHi, ushort* __restrict__ WcLo,
                            const int* __restrict__ dst, int* __restrict__ counts, int E) {
  const int b = blockIdx.x, tid = threadIdx.x;
  if (b < 256) {
    int i = b * 256 + tid;
    float w = Wn[i];
    ushort h = f2bf(w);
    WnHi[i] = h;
    WnLo[i] = f2bf(w - bf2f(h));
  } else if (b < 512) {
    int i = (b - 256) * 256 + tid;
    float w = Wc[i];
    ushort h = f2bf(w);
    WcHi[i] = h;
    WcLo[i] = f2bf(w - bf2f(h));
  } else {
    int e = (b - 512) * 256 + tid;
    if (e < E) atomicAdd(&counts[dst[e]], 1);
  }
}

// single-block scan over C counts -> exclusive offsets[0..C], cursor copy
__global__ void scan_kernel(const int* __restrict__ counts, int* __restrict__ offsets,
                            int* __restrict__ cursor, int C) {
  __shared__ int wsum[16];
  int tid = threadIdx.x;
  int lane = tid & 63, wid = tid >> 6;
  int base = 0;
  for (int start = 0; start < C; start += 1024) {
    int idx = start + tid;
    int val = (idx < C) ? counts[idx] : 0;
    int x = val;
#pragma unroll
    for (int off = 1; off < 64; off <<= 1) {
      int y = __shfl_up(x, off);
      if (lane >= off) x += y;
    }
    if (lane == 63) wsum[wid] = x;
    __syncthreads();
    int add = base;
    for (int w = 0; w < wid; ++w) add += wsum[w];
    if (idx < C) {
      int excl = add + x - val;
      offsets[idx] = excl;
      cursor[idx]  = excl;
    }
    int tot = 0;
#pragma unroll
    for (int w = 0; w < 16; ++w) tot += wsum[w];
    __syncthreads();
    base += tot;
  }
  if (tid == 0) offsets[C] = base;
}

__global__ void fill_kernel(const int* __restrict__ src, const int* __restrict__ dst,
                            int* __restrict__ cursor, int* __restrict__ srcs_sorted, int E) {
  int e = blockIdx.x * blockDim.x + threadIdx.x;
  if (e < E) {
    int d = dst[e];
    int pos = atomicAdd(&cursor[d], 1);
    srcs_sorted[pos] = src[e];
  }
}

// ---------------- persistent-W MFMA GEMM, ablation template ----------------
// V0 full | V1 no global stores | V2 no compute (staging only) | V3 no staging
template <int V>
__global__ __launch_bounds__(1024, 1) void gemm_persist_t(
    const float* __restrict__ Xc, const ushort* __restrict__ WcHi,
    const ushort* __restrict__ WcLo, ushort* __restrict__ cproj, int MC, int GC,
    const float* __restrict__ Xn, const ushort* __restrict__ WnHi,
    const ushort* __restrict__ WnLo, ushort* __restrict__ nproj,
    ushort* __restrict__ nxbf, int MN) {
  constexpr bool STAGE = (V != 3);               // load4 + f2bf + ds_write
  constexpr bool XBF   = (V == 0 || V == 2);     // xbf global store
  constexpr bool COMP  = (V != 2);               // ds_read + MFMA
  constexpr bool PROJ  = (V == 0 || V == 3);     // proj global store
  constexpr int PITCH = 264;              // ushorts per LDS row (528B = 33*16B)
  __shared__ ushort Xs[2][64 * PITCH];    // 2 x 33.8 KB double buffer
  const int tid = threadIdx.x;
  const int wv = tid >> 6, lane = tid & 63;   // wv 0..15: owns cols wv*16..+15
  const int q = lane >> 4, nidx = lane & 15;
  const int GN = gridDim.x - GC;

  const float* X; const ushort *Whi, *Wlo; ushort *proj, *xb; int M, nb, lb;
  if ((int)blockIdx.x < GC) {
    X = Xc; Whi = WcHi; Wlo = WcLo; proj = cproj; xb = nullptr; M = MC;
    nb = GC; lb = blockIdx.x;
  } else {
    X = Xn; Whi = WnHi; Wlo = WnLo; proj = nproj; xb = nxbf; M = MN;
    nb = GN; lb = blockIdx.x - GC;
  }
  const int nt = (M + 63) >> 6;
  const int qt = nt / nb, rt = nt % nb;
  const int first = lb * qt + (lb < rt ? lb : rt);
  const int cnt = qt + (lb < rt ? 1 : 0);
  if (cnt <= 0) return;

  // persistent W fragments: 16 cols/wave, hi+lo, 8 k-slices = 64 VGPRs
  bfrag bhi[8], blo[8];
#pragma unroll
  for (int ks = 0; ks < 8; ++ks) {
    const size_t off = (size_t)(wv * 16 + nidx) * H + ks * 32 + q * 8;
    bhi[ks] = *(const bfrag*)(Whi + off);
    blo[ks] = *(const bfrag*)(Wlo + off);
  }
  if constexpr (!COMP) {  // keep W loads alive in V2 (rule 17: anti-DCE)
    float ws = 0.f;
#pragma unroll
    for (int ks = 0; ks < 8; ++ks)
      ws += bf2f((ushort)bhi[ks][0]) + bf2f((ushort)blo[ks][0]);
    asm volatile("" ::"v"(ws));
  }

  float4 xr[4];  // staging: 64x256 fp32 tile / 1024 thr = 4 float4 each
  auto load4 = [&](int tile) {
#pragma unroll
    for (int j = 0; j < 4; ++j) {
      const int flat = j * 4096 + tid * 4;
      int gr = tile * 64 + (flat >> 8);
      if (gr >= M) gr = M - 1;
      xr[j] = *(const float4*)(X + (size_t)gr * H + (flat & 255));
    }
  };
  auto writebuf = [&](int p, int tile) {
#pragma unroll
    for (int j = 0; j < 4; ++j) {
      const int flat = j * 4096 + tid * 4;
      const int r = flat >> 8, k = flat & 255;
      ushort4 b4;
      b4.x = f2bf(xr[j].x); b4.y = f2bf(xr[j].y);
      b4.z = f2bf(xr[j].z); b4.w = f2bf(xr[j].w);
      *(ushort4*)&Xs[p][r * PITCH + k] = b4;
      if constexpr (XBF) {
        if (xb) {
          const int gr = tile * 64 + r;
          *(ushort4*)(xb + (size_t)gr * H + k) = b4;
        }
      }
    }
  };

  if constexpr (STAGE) {
    load4(first);
    writebuf(0, first);
  }
  int p = 0;
  for (int t = 0; t < cnt; ++t) {
    __syncthreads();
    const int tile = first + t;
    const bool more = (t + 1 < cnt);
    if constexpr (STAGE) { if (more) load4(tile + 1); }

    ffrag acc[4];
#pragma unroll
    for (int i = 0; i < 4; ++i) acc[i] = (ffrag)(0.f);
    if constexpr (COMP) {
#pragma unroll
      for (int ks = 0; ks < 8; ++ks) {
        bfrag a[4];
#pragma unroll
        for (int i = 0; i < 4; ++i)
          a[i] = *(const bfrag*)&Xs[p][(16 * i + nidx) * PITCH + ks * 32 + q * 8];
#pragma unroll
        for (int i = 0; i < 4; ++i) {
          acc[i] = __builtin_amdgcn_mfma_f32_16x16x32_bf16(a[i], bhi[ks], acc[i], 0, 0, 0);
          acc[i] = __builtin_amdgcn_mfma_f32_16x16x32_bf16(a[i], blo[ks], acc[i], 0, 0, 0);
        }
      }
    }

    if constexpr (PROJ) {
      const int row0 = tile * 64;
#pragma unroll
      for (int i = 0; i < 4; ++i)
#pragma unroll
        for (int r = 0; r < 4; ++r) {
          const int grow = row0 + 16 * i + q * 4 + r;
          if (grow < M)
            proj[(size_t)grow * H + wv * 16 + nidx] = f2bf(acc[i][r]);
        }
    } else if constexpr (COMP) {  // V1: keep MFMA live without stores
      float s = 0.f;
#pragma unroll
      for (int i = 0; i < 4; ++i)
        s += acc[i][0] + acc[i][1] + acc[i][2] + acc[i][3];
      asm volatile("" ::"v"(s));
    }

    if constexpr (STAGE) { if (more) writebuf(p ^ 1, tile + 1); }
    p ^= 1;
  }
}

// ---------------- split-wave flash edge kernel ----------------
__device__ __forceinline__ float fast_tanh(float x) {
  float e = __builtin_amdgcn_exp2f(x * 2.8853900817779268f);  // e^{2x}
  float t = __builtin_amdgcn_rcpf(e + 1.f);
  return __builtin_fmaf(-2.f, t, 1.f);
}

__global__ __launch_bounds__(256) void edge_flash_kernel(
    const ushort* __restrict__ news_projbf, const ushort* __restrict__ company_projbf,
    const float* __restrict__ v, const int* __restrict__ offsets,
    const int* __restrict__ srcs, const ushort* __restrict__ news_xbf,
    float* __restrict__ out) {
  const int c = blockIdx.x;
  const int tid = threadIdx.x;
  const int sl = tid & 31;
  const int hw = tid >> 5;
  __shared__ float cp[H];
  __shared__ float mW[8], lW[8];
  __shared__ float OW[8][H];
  cp[tid] = bf2f(company_projbf[(size_t)c * H + tid]);
  __syncthreads();
  const float4 va = *(const float4*)(v + sl * 8);
  const float4 vb = *(const float4*)(v + sl * 8 + 4);
  const float4 ca = *(const float4*)&cp[sl * 8];
  const float4 cb = *(const float4*)&cp[sl * 8 + 4];
  const float vv[8] = {va.x, va.y, va.z, va.w, vb.x, vb.y, vb.z, vb.w};
  const float cq[8] = {ca.x, ca.y, ca.z, ca.w, cb.x, cb.y, cb.z, cb.w};
  const int beg = offsets[c], end = offsets[c + 1];

  float m = -INFINITY, l = 0.f;
  float O[8] = {0.f, 0.f, 0.f, 0.f, 0.f, 0.f, 0.f, 0.f};

  int i = beg + hw;
  if (i < end) {
    int s = srcs[i];
    bfrag pr = *(const bfrag*)(news_projbf + (size_t)s * H + sl * 8);
    bfrag xr = *(const bfrag*)(news_xbf + (size_t)s * H + sl * 8);
    for (;;) {
      const int inext = i + 8;
      const bool more = (inext < end);
      bfrag prn, xrn;
      if (more) {
        int sn = srcs[inext];
        prn = *(const bfrag*)(news_projbf + (size_t)sn * H + sl * 8);
        xrn = *(const bfrag*)(news_xbf + (size_t)sn * H + sl * 8);
      }
      float r = 0.f;
#pragma unroll
      for (int j = 0; j < 8; ++j)
        r += fast_tanh(bf2f((ushort)pr[j]) + cq[j]) * vv[j];
#pragma unroll
      for (int off = 16; off > 0; off >>= 1) r += __shfl_xor(r, off);
      const float mnew = fmaxf(m, r);
      const float alpha = __expf(m - mnew);
      const float pa = __expf(r - mnew);
      l = l * alpha + pa;
#pragma unroll
      for (int j = 0; j < 8; ++j)
        O[j] = O[j] * alpha + pa * bf2f((ushort)xr[j]);
      m = mnew;
      i = inext;
      if (!more) break;
      pr = prn; xr = xrn;
    }
  }

  if (sl == 0) { mW[hw] = m; lW[hw] = l; }
  *(float4*)&OW[hw][sl * 8]     = make_float4(O[0], O[1], O[2], O[3]);
  *(float4*)&OW[hw][sl * 8 + 4] = make_float4(O[4], O[5], O[6], O[7]);
  __syncthreads();
  float mstar = -INFINITY;
#pragma unroll
  for (int w = 0; w < 8; ++w) mstar = fmaxf(mstar, mW[w]);
  float denom = 0.f, val = 0.f;
#pragma unroll
  for (int w = 0; w < 8; ++w) {
    const float sc = (lW[w] > 0.f) ? __expf(mW[w] - mstar) : 0.f;
    denom += lW[w] * sc;
    val += OW[w][tid] * sc;
  }
  out[(size_t)c * H + tid] = val / fmaxf(denom, 1e-9f);
}

// ---------------- launch ----------------
extern "C" void kernel_launch(void* const* d_in, const int* in_sizes, int n_in,
                              void* d_out, int out_size, void* d_ws, size_t ws_size,
                              hipStream_t stream) {
  const float* news_x    = (const float*)d_in[0];
  const float* company_x = (const float*)d_in[1];
  const float* W_news    = (const float*)d_in[2];
  const float* W_company = (const float*)d_in[3];
  const float* v         = (const float*)d_in[4];
  const int*   src       = (const int*)d_in[5];
  const int*   dst       = (const int*)d_in[6];
  const int N = in_sizes[0] / H;
  const int C = in_sizes[1] / H;
  const int E = in_sizes[5];
  float* out = (float*)d_out;

  char* p = (char*)d_ws;
  ushort* news_projbf    = (ushort*)p; p += (size_t)N * H * sizeof(ushort);
  ushort* news_xbf       = (ushort*)p; p += (size_t)N * H * sizeof(ushort);
  ushort* company_projbf = (ushort*)p; p += (size_t)C * H * sizeof(ushort);
  int*    srcs_sorted    = (int*)p;    p += (size_t)E * sizeof(int);
  ushort* Wn_hi          = (ushort*)p; p += (size_t)H * H * sizeof(ushort);
  ushort* Wn_lo          = (ushort*)p; p += (size_t)H * H * sizeof(ushort);
  ushort* Wc_hi          = (ushort*)p; p += (size_t)H * H * sizeof(ushort);
  ushort* Wc_lo          = (ushort*)p; p += (size_t)H * H * sizeof(ushort);
  int*    counts         = (int*)p;    p += (size_t)C * sizeof(int);
  int*    offsets        = (int*)p;    p += (size_t)(C + 1) * sizeof(int);
  int*    cursor         = (int*)p;    p += (size_t)C * sizeof(int);

  hipMemsetAsync(counts, 0, (size_t)C * sizeof(int), stream);
  prep_kernel<<<512 + (E + 255) / 256, 256, 0, stream>>>(
      W_news, W_company, Wn_hi, Wn_lo, Wc_hi, Wc_lo, dst, counts, E);
  scan_kernel<<<1, 1024, 0, stream>>>(counts, offsets, cursor, C);
  fill_kernel<<<(E + 255) / 256, 256, 0, stream>>>(src, dst, cursor, srcs_sorted, E);

  const int GC = 12, GN = 244;
  // --- ablation dispatches (garbage outputs, fully overwritten by V0) ---
  gemm_persist_t<1><<<GC + GN, 1024, 0, stream>>>(   // no global stores
      company_x, Wc_hi, Wc_lo, company_projbf, C, GC,
      news_x, Wn_hi, Wn_lo, news_projbf, news_xbf, N);
  gemm_persist_t<2><<<GC + GN, 1024, 0, stream>>>(   // staging only
      company_x, Wc_hi, Wc_lo, company_projbf, C, GC,
      news_x, Wn_hi, Wn_lo, news_projbf, news_xbf, N);
  gemm_persist_t<3><<<GC + GN, 1024, 0, stream>>>(   // no staging
      company_x, Wc_hi, Wc_lo, company_projbf, C, GC,
      news_x, Wn_hi, Wn_lo, news_projbf, news_xbf, N);
  // --- real run: overwrites every proj/xbf row ---
  gemm_persist_t<0><<<GC + GN, 1024, 0, stream>>>(
      company_x, Wc_hi, Wc_lo, company_projbf, C, GC,
      news_x, Wn_hi, Wn_lo, news_projbf, news_xbf, N);

  edge_flash_kernel<<<C, 256, 0, stream>>>(news_projbf, company_projbf, v, offsets,
                                           srcs_sorted, news_xbf, out);
}

// Round 10
// 534.806 us; speedup vs baseline: 1.3362x; 1.3362x over previous
//
#include <hip/hip_runtime.h>
#include <hip/hip_bf16.h>
#include <cmath>
#include <cstdint>

// AttentionPoolingAggregator — MI355X round 14
//  * Diagnosis from r13 ablation arithmetic: V1+V2+V3 = 181us << 252us
//    (additive bound) -> phase COUPLING, not bandwidth. Cause: vmcnt retires
//    IN ORDER; the 16 scattered 2B proj stores/lane retire over ~1-2
//    iterations, and every next-tile load-wait (writebuf) must drain them
//    first -> memory phases serialized. r8's coalesced-store fix was masked
//    by its own full-drain __syncthreads.
//  * Fix: (1) acc -> bf16 into a 3rd LDS buffer right after each wave's
//    MFMAs (no extra barrier), proj stored as 32B/thread contiguous
//    (full 64B lines, fast retirement); (2) loads issued BEFORE stores each
//    iter (FIFO: load-wait never drains stores); (3) lgkm-only barriers.
//  * edge_flash / prep / scan / fill unchanged from r12.

#define H 256

typedef __attribute__((ext_vector_type(8))) short bfrag;  // 8 bf16 (4 VGPRs)
typedef __attribute__((ext_vector_type(4))) float ffrag;  // 4 fp32 acc

__device__ __forceinline__ ushort f2bf(float f) {  // fp32 -> bf16 RNE
  uint u = __float_as_uint(f);
  uint r = u + 0x7FFFu + ((u >> 16) & 1u);
  return (ushort)(r >> 16);
}
__device__ __forceinline__ float bf2f(ushort h) {
  return __uint_as_float((uint)h << 16);
}

// ---------------- prep: wsplit(W_news) | wsplit(W_company) | count histogram ----------------
__global__ void prep_kernel(const float* __restrict__ Wn, const float* __restrict__ Wc,
                            ushort* __restrict__ WnHi, ushort* __restrict__ WnLo,
                            ushort* __restrict__ WcHi, ushort* __restrict__ WcLo,
                            const int* __restrict__ dst, int* __restrict__ counts, int E) {
  const int b = blockIdx.x, tid = threadIdx.x;
  if (b < 256) {
    int i = b * 256 + tid;
    float w = Wn[i];
    ushort h = f2bf(w);
    WnHi[i] = h;
    WnLo[i] = f2bf(w - bf2f(h));
  } else if (b < 512) {
    int i = (b - 256) * 256 + tid;
    float w = Wc[i];
    ushort h = f2bf(w);
    WcHi[i] = h;
    WcLo[i] = f2bf(w - bf2f(h));
  } else {
    int e = (b - 512) * 256 + tid;
    if (e < E) atomicAdd(&counts[dst[e]], 1);
  }
}

// single-block scan over C counts -> exclusive offsets[0..C], cursor copy
__global__ void scan_kernel(const int* __restrict__ counts, int* __restrict__ offsets,
                            int* __restrict__ cursor, int C) {
  __shared__ int wsum[16];
  int tid = threadIdx.x;
  int lane = tid & 63, wid = tid >> 6;
  int base = 0;
  for (int start = 0; start < C; start += 1024) {
    int idx = start + tid;
    int val = (idx < C) ? counts[idx] : 0;
    int x = val;
#pragma unroll
    for (int off = 1; off < 64; off <<= 1) {
      int y = __shfl_up(x, off);
      if (lane >= off) x += y;
    }
    if (lane == 63) wsum[wid] = x;
    __syncthreads();
    int add = base;
    for (int w = 0; w < wid; ++w) add += wsum[w];
    if (idx < C) {
      int excl = add + x - val;
      offsets[idx] = excl;
      cursor[idx]  = excl;
    }
    int tot = 0;
#pragma unroll
    for (int w = 0; w < 16; ++w) tot += wsum[w];
    __syncthreads();
    base += tot;
  }
  if (tid == 0) offsets[C] = base;
}

__global__ void fill_kernel(const int* __restrict__ src, const int* __restrict__ dst,
                            int* __restrict__ cursor, int* __restrict__ srcs_sorted, int E) {
  int e = blockIdx.x * blockDim.x + threadIdx.x;
  if (e < E) {
    int d = dst[e];
    int pos = atomicAdd(&cursor[d], 1);
    srcs_sorted[pos] = src[e];
  }
}

// ---------------- persistent-W MFMA GEMM, store-decoupled epilogue ----------------
__global__ __launch_bounds__(1024, 1) void gemm_persist(
    const float* __restrict__ Xc, const ushort* __restrict__ WcHi,
    const ushort* __restrict__ WcLo, ushort* __restrict__ cproj, int MC, int GC,
    const float* __restrict__ Xn, const ushort* __restrict__ WnHi,
    const ushort* __restrict__ WnLo, ushort* __restrict__ nproj,
    ushort* __restrict__ nxbf, int MN) {
  constexpr int PITCH = 264;              // ushorts per LDS row (528B = 33*16B)
  __shared__ ushort Xs[2][64 * PITCH];    // 2 x 33.8 KB staging double buffer
  __shared__ ushort Bx[64 * PITCH];       // 33.8 KB epilogue bounce buffer
  const int tid = threadIdx.x;
  const int wv = tid >> 6, lane = tid & 63;   // wv 0..15: owns cols wv*16..+15
  const int q = lane >> 4, nidx = lane & 15;
  const int GN = gridDim.x - GC;

  const float* X; const ushort *Whi, *Wlo; ushort *proj, *xb; int M, nb, lb;
  if ((int)blockIdx.x < GC) {
    X = Xc; Whi = WcHi; Wlo = WcLo; proj = cproj; xb = nullptr; M = MC;
    nb = GC; lb = blockIdx.x;
  } else {
    X = Xn; Whi = WnHi; Wlo = WnLo; proj = nproj; xb = nxbf; M = MN;
    nb = GN; lb = blockIdx.x - GC;
  }
  const int nt = (M + 63) >> 6;                       // tiles for this side
  const int qt = nt / nb, rt = nt % nb;
  const int first = lb * qt + (lb < rt ? lb : rt);    // contiguous chunk
  const int cnt = qt + (lb < rt ? 1 : 0);
  if (cnt <= 0) return;

  // lgkm-only barrier: never drains the VMEM (load/store) queues.
  auto lgkm_bar = []() {
    asm volatile("s_waitcnt lgkmcnt(0)" ::: "memory");
    __builtin_amdgcn_sched_barrier(0);
    __builtin_amdgcn_s_barrier();
    __builtin_amdgcn_sched_barrier(0);
  };

  // persistent W fragments: 16 cols/wave, hi+lo, 8 k-slices = 64 VGPRs
  bfrag bhi[8], blo[8];
#pragma unroll
  for (int ks = 0; ks < 8; ++ks) {
    const size_t off = (size_t)(wv * 16 + nidx) * H + ks * 32 + q * 8;
    bhi[ks] = *(const bfrag*)(Whi + off);
    blo[ks] = *(const bfrag*)(Wlo + off);
  }

  float4 xr[4];  // staging: 64x256 fp32 tile / 1024 thr = 4 float4 each
  auto load4 = [&](int tile) {
#pragma unroll
    for (int j = 0; j < 4; ++j) {
      const int flat = j * 4096 + tid * 4;            // fully coalesced
      int gr = tile * 64 + (flat >> 8);
      if (gr >= M) gr = M - 1;                        // company tail: dup reads
      xr[j] = *(const float4*)(X + (size_t)gr * H + (flat & 255));
    }
  };
  auto writebuf = [&](int p, int tile) {
#pragma unroll
    for (int j = 0; j < 4; ++j) {
      const int flat = j * 4096 + tid * 4;
      const int r = flat >> 8, k = flat & 255;
      ushort4 b4;
      b4.x = f2bf(xr[j].x); b4.y = f2bf(xr[j].y);
      b4.z = f2bf(xr[j].z); b4.w = f2bf(xr[j].w);
      *(ushort4*)&Xs[p][r * PITCH + k] = b4;
      if (xb) {
        const int gr = tile * 64 + r;                 // news: full tiles, no clamp
        *(ushort4*)(xb + (size_t)gr * H + k) = b4;
      }
    }
  };

  // prologue: stage first tile into buffer 0
  load4(first);
  writebuf(0, first);
  int p = 0;
  for (int t = 0; t < cnt; ++t) {
    lgkm_bar();                                       // buf[p] staged & visible
    const int tile = first + t;
    const bool more = (t + 1 < cnt);
    if (more) load4(tile + 1);                        // loads FIRST in vmcnt FIFO

    ffrag acc[4];
#pragma unroll
    for (int i = 0; i < 4; ++i) acc[i] = (ffrag)(0.f);
#pragma unroll
    for (int ks = 0; ks < 8; ++ks) {
      bfrag a[4];
#pragma unroll
      for (int i = 0; i < 4; ++i)
        a[i] = *(const bfrag*)&Xs[p][(16 * i + nidx) * PITCH + ks * 32 + q * 8];
#pragma unroll
      for (int i = 0; i < 4; ++i) {
        acc[i] = __builtin_amdgcn_mfma_f32_16x16x32_bf16(a[i], bhi[ks], acc[i], 0, 0, 0);
        acc[i] = __builtin_amdgcn_mfma_f32_16x16x32_bf16(a[i], blo[ks], acc[i], 0, 0, 0);
      }
    }

    // bounce acc -> bf16 into Bx right after own MFMAs (no barrier needed:
    // Bx's previous readers all retired at this iteration's lgkm_bar).
#pragma unroll
    for (int i = 0; i < 4; ++i)
#pragma unroll
      for (int r = 0; r < 4; ++r)
        Bx[(16 * i + q * 4 + r) * PITCH + wv * 16 + nidx] = f2bf(acc[i][r]);
    lgkm_bar();                                       // all bounce writes visible

    // coalesced proj store: 16 thr/row, 32B/thread contiguous (full 64B lines)
    {
      const int row = tid >> 4, seg = tid & 15;
      const int grow = tile * 64 + row;
      if (grow < M) {
        bfrag v0 = *(const bfrag*)&Bx[row * PITCH + seg * 16];
        bfrag v1 = *(const bfrag*)&Bx[row * PITCH + seg * 16 + 8];
        *(bfrag*)(proj + (size_t)grow * H + seg * 16) = v0;      // issued AFTER
        *(bfrag*)(proj + (size_t)grow * H + seg * 16 + 8) = v1;  // the t+1 loads
      }
    }

    if (more) writebuf(p ^ 1, tile + 1);  // vmcnt-wait retires loads only
    p ^= 1;
  }
}

// ---------------- split-wave flash edge kernel ----------------
// 4 instrs (2 trans), no IEEE div:  tanh(x) = 1 - 2*rcp(exp2(2x*log2e)+1)
__device__ __forceinline__ float fast_tanh(float x) {
  float e = __builtin_amdgcn_exp2f(x * 2.8853900817779268f);  // e^{2x}
  float t = __builtin_amdgcn_rcpf(e + 1.f);
  return __builtin_fmaf(-2.f, t, 1.f);
}

__global__ __launch_bounds__(256) void edge_flash_kernel(
    const ushort* __restrict__ news_projbf, const ushort* __restrict__ company_projbf,
    const float* __restrict__ v, const int* __restrict__ offsets,
    const int* __restrict__ srcs, const ushort* __restrict__ news_xbf,
    float* __restrict__ out) {
  const int c = blockIdx.x;
  const int tid = threadIdx.x;
  const int sl = tid & 31;   // sub-lane within half-wave (owns dims sl*8..sl*8+7)
  const int hw = tid >> 5;   // half-wave id 0..7 (owns edges beg+hw, +8, +16, ...)
  __shared__ float cp[H];
  __shared__ float mW[8], lW[8];
  __shared__ float OW[8][H];  // 8 KB
  cp[tid] = bf2f(company_projbf[(size_t)c * H + tid]);
  __syncthreads();
  const float4 va = *(const float4*)(v + sl * 8);
  const float4 vb = *(const float4*)(v + sl * 8 + 4);
  const float4 ca = *(const float4*)&cp[sl * 8];
  const float4 cb = *(const float4*)&cp[sl * 8 + 4];
  const float vv[8] = {va.x, va.y, va.z, va.w, vb.x, vb.y, vb.z, vb.w};
  const float cq[8] = {ca.x, ca.y, ca.z, ca.w, cb.x, cb.y, cb.z, cb.w};
  const int beg = offsets[c], end = offsets[c + 1];

  float m = -INFINITY, l = 0.f;
  float O[8] = {0.f, 0.f, 0.f, 0.f, 0.f, 0.f, 0.f, 0.f};

  int i = beg + hw;
  if (i < end) {
    int s = srcs[i];
    bfrag pr = *(const bfrag*)(news_projbf + (size_t)s * H + sl * 8);
    bfrag xr = *(const bfrag*)(news_xbf + (size_t)s * H + sl * 8);
    for (;;) {
      const int inext = i + 8;
      const bool more = (inext < end);  // half-wave uniform
      bfrag prn, xrn;
      if (more) {  // prefetch next edge while computing current
        int sn = srcs[inext];
        prn = *(const bfrag*)(news_projbf + (size_t)sn * H + sl * 8);
        xrn = *(const bfrag*)(news_xbf + (size_t)sn * H + sl * 8);
      }
      float r = 0.f;
#pragma unroll
      for (int j = 0; j < 8; ++j)
        r += fast_tanh(bf2f((ushort)pr[j]) + cq[j]) * vv[j];
#pragma unroll
      for (int off = 16; off > 0; off >>= 1) r += __shfl_xor(r, off);
      const float mnew = fmaxf(m, r);
      const float alpha = __expf(m - mnew);  // first iter: exp(-inf)=0
      const float pa = __expf(r - mnew);
      l = l * alpha + pa;
#pragma unroll
      for (int j = 0; j < 8; ++j)
        O[j] = O[j] * alpha + pa * bf2f((ushort)xr[j]);
      m = mnew;
      i = inext;
      if (!more) break;
      pr = prn; xr = xrn;
    }
  }

  // ---- merge 8 half-waves ----
  if (sl == 0) { mW[hw] = m; lW[hw] = l; }
  *(float4*)&OW[hw][sl * 8]     = make_float4(O[0], O[1], O[2], O[3]);
  *(float4*)&OW[hw][sl * 8 + 4] = make_float4(O[4], O[5], O[6], O[7]);
  __syncthreads();
  float mstar = -INFINITY;
#pragma unroll
  for (int w = 0; w < 8; ++w) mstar = fmaxf(mstar, mW[w]);
  float denom = 0.f, val = 0.f;
#pragma unroll
  for (int w = 0; w < 8; ++w) {
    const float sc = (lW[w] > 0.f) ? __expf(mW[w] - mstar) : 0.f;
    denom += lW[w] * sc;
    val += OW[w][tid] * sc;
  }
  out[(size_t)c * H + tid] = val / fmaxf(denom, 1e-9f);
}

// ---------------- launch ----------------
extern "C" void kernel_launch(void* const* d_in, const int* in_sizes, int n_in,
                              void* d_out, int out_size, void* d_ws, size_t ws_size,
                              hipStream_t stream) {
  const float* news_x    = (const float*)d_in[0];
  const float* company_x = (const float*)d_in[1];
  const float* W_news    = (const float*)d_in[2];
  const float* W_company = (const float*)d_in[3];
  const float* v         = (const float*)d_in[4];
  const int*   src       = (const int*)d_in[5];
  const int*   dst       = (const int*)d_in[6];
  const int N = in_sizes[0] / H;
  const int C = in_sizes[1] / H;
  const int E = in_sizes[5];
  float* out = (float*)d_out;

  char* p = (char*)d_ws;
  ushort* news_projbf    = (ushort*)p; p += (size_t)N * H * sizeof(ushort);
  ushort* news_xbf       = (ushort*)p; p += (size_t)N * H * sizeof(ushort);
  ushort* company_projbf = (ushort*)p; p += (size_t)C * H * sizeof(ushort);
  int*    srcs_sorted    = (int*)p;    p += (size_t)E * sizeof(int);
  ushort* Wn_hi          = (ushort*)p; p += (size_t)H * H * sizeof(ushort);
  ushort* Wn_lo          = (ushort*)p; p += (size_t)H * H * sizeof(ushort);
  ushort* Wc_hi          = (ushort*)p; p += (size_t)H * H * sizeof(ushort);
  ushort* Wc_lo          = (ushort*)p; p += (size_t)H * H * sizeof(ushort);
  int*    counts         = (int*)p;    p += (size_t)C * sizeof(int);
  int*    offsets        = (int*)p;    p += (size_t)(C + 1) * sizeof(int);
  int*    cursor         = (int*)p;    p += (size_t)C * sizeof(int);

  hipMemsetAsync(counts, 0, (size_t)C * sizeof(int), stream);
  prep_kernel<<<512 + (E + 255) / 256, 256, 0, stream>>>(
      W_news, W_company, Wn_hi, Wn_lo, Wc_hi, Wc_lo, dst, counts, E);
  scan_kernel<<<1, 1024, 0, stream>>>(counts, offsets, cursor, C);
  fill_kernel<<<(E + 255) / 256, 256, 0, stream>>>(src, dst, cursor, srcs_sorted, E);

  // 256 blocks x 1024 thr, 1 block/CU. company 157/12=13.1, news 3125/244=12.8.
  const int GC = 12, GN = 244;
  gemm_persist<<<GC + GN, 1024, 0, stream>>>(
      company_x, Wc_hi, Wc_lo, company_projbf, C, GC,
      news_x, Wn_hi, Wn_lo, news_projbf, news_xbf, N);

  edge_flash_kernel<<<C, 256, 0, stream>>>(news_projbf, company_projbf, v, offsets,
                                           srcs_sorted, news_xbf, out);
}